// Round 1
// 211.744 us; speedup vs baseline: 1.0457x; 1.0457x over previous
//
#include <hip/hip_runtime.h>
#include <hip/hip_bf16.h>
#include <stdint.h>

#define BATCH 32
#define SRCN 1024
#define SEQL 128
#define CTXN 5
#define DMOD 512

typedef __attribute__((ext_vector_type(8))) short short8;
typedef __attribute__((ext_vector_type(4))) float floatx4;

typedef __attribute__((address_space(3))) void lds_t;
typedef __attribute__((address_space(1))) void glb_t;

__device__ __forceinline__ void gload_lds16(const void* g, void* l) {
    __builtin_amdgcn_global_load_lds((const glb_t*)g, (lds_t*)l, 16, 0, 0);
}

__device__ __forceinline__ ushort f2b(float f) {
    __hip_bfloat16 h = __float2bfloat16(f);
    return *reinterpret_cast<ushort*>(&h);
}

// Swizzled LDS slot for (tile-local row m, k-seg sg): slot = m*8 + (sg^(m&7)),
// slot = 8 ushorts (16B). Staging chunk cc (1KB = 8 rows x 64k): lane i stages
// row cc*8+(i>>3), k-seg (i&7)^(i>>3) -> 8 contiguous 128B runs, and the LDS
// dest is exactly chunkbase + lane*16 (wave-uniform base + lane*size).
#define LSLOT(m, sg) ((((m) << 3) | ((sg) ^ ((m) & 7))) << 3)

// ---------------------------------------------------------------------------
// Merged gather: blocks [0,4096) yce gather; [4096,4416) P_w transpose;
// [4416,8512) F gather -> xe + xet. All independent; one launch.
// ---------------------------------------------------------------------------
__global__ __launch_bounds__(256) void k_gather(
    const int* __restrict__ yc, const float* __restrict__ G,
    ushort* __restrict__ yce,
    const float* __restrict__ Pw, ushort* __restrict__ Pwt,
    const int* __restrict__ x, const float* __restrict__ F,
    ushort* __restrict__ xe, ushort* __restrict__ xet)
{
    __shared__ char smem[17408];   // max(64*68*4, 64*72*2)
    const int tid = threadIdx.x;
    const int bid = blockIdx.x;
    if (bid < 4096) {
        // ---- gather yce[b][s][c*512 + d] bf16 ----
        const int r = bid;                   // b*128+s
        const int b = r >> 7, s = r & 127;
        for (int i = tid; i < 640; i += 256) {
            const int c = i >> 7;            // context slot 0..4
            const int tok = yc[b * (SEQL * CTXN) + s * CTXN + c];
            const float4 v = *(const float4*)(G + (size_t)tok * DMOD + (i & 127) * 4);
            ushort4 o;
            o.x = f2b(v.x); o.y = f2b(v.y); o.z = f2b(v.z); o.w = f2b(v.w);
            *(ushort4*)(yce + (size_t)r * 2560 + i * 4) = o;
        }
    } else if (bid < 4416) {
        // ---- transpose P_w [2560][512] -> Pwt [512][2560] bf16 ----
        float* t = (float*)smem;             // [64][68]
        const int id = bid - 4096;           // 0..319
        const int k0 = (id % 40) * 64, n0 = (id / 40) * 64;
        #pragma unroll
        for (int it = 0; it < 4; ++it) {
            const int c = tid + it * 256;
            const int kr = c >> 4, c4 = c & 15;
            const float4 v = *(const float4*)(Pw + (size_t)(k0 + kr) * DMOD + n0 + c4 * 4);
            t[kr * 68 + c4 * 4 + 0] = v.x; t[kr * 68 + c4 * 4 + 1] = v.y;
            t[kr * 68 + c4 * 4 + 2] = v.z; t[kr * 68 + c4 * 4 + 3] = v.w;
        }
        __syncthreads();
        #pragma unroll
        for (int it = 0; it < 2; ++it) {
            const int c = tid + it * 256;
            const int n = c >> 3, seg = c & 7;
            ushort4 o0, o1;
            o0.x = f2b(t[(seg * 8 + 0) * 68 + n]); o0.y = f2b(t[(seg * 8 + 1) * 68 + n]);
            o0.z = f2b(t[(seg * 8 + 2) * 68 + n]); o0.w = f2b(t[(seg * 8 + 3) * 68 + n]);
            o1.x = f2b(t[(seg * 8 + 4) * 68 + n]); o1.y = f2b(t[(seg * 8 + 5) * 68 + n]);
            o1.z = f2b(t[(seg * 8 + 6) * 68 + n]); o1.w = f2b(t[(seg * 8 + 7) * 68 + n]);
            ushort* dst = Pwt + (size_t)(n0 + n) * 2560 + k0 + seg * 8;
            *(ushort4*)dst = o0; *(ushort4*)(dst + 4) = o1;
        }
    } else {
        // ---- gather F rows -> xe[b][x][d] AND xet[b][d][x] bf16 ----
        ushort* t = (ushort*)smem;           // [64][72]
        const int id = bid - 4416;           // 0..4095
        const int z = id >> 7;               // batch
        const int rem = id & 127;
        const int x0 = (rem & 15) * 64, d0 = (rem >> 4) * 64;
        #pragma unroll
        for (int it = 0; it < 4; ++it) {
            const int c = tid + it * 256;    // 1024 chunks: 64 rows x 16 float4
            const int row = c >> 4, seg = c & 15;
            const int tok = x[z * SRCN + x0 + row];
            const float4 v = *(const float4*)(F + (size_t)tok * DMOD + d0 + seg * 4);
            ushort4 o;
            o.x = f2b(v.x); o.y = f2b(v.y); o.z = f2b(v.z); o.w = f2b(v.w);
            *(ushort4*)&t[row * 72 + seg * 4] = o;
            *(ushort4*)(xe + (size_t)(z * SRCN + x0 + row) * DMOD + d0 + seg * 4) = o;
        }
        __syncthreads();
        #pragma unroll
        for (int it = 0; it < 2; ++it) {
            const int c = tid + it * 256;    // 512 outs: 64 d x 8 seg
            const int d = c >> 3, seg = c & 7;
            ushort4 o0, o1;
            o0.x = t[(seg * 8 + 0) * 72 + d]; o0.y = t[(seg * 8 + 1) * 72 + d];
            o0.z = t[(seg * 8 + 2) * 72 + d]; o0.w = t[(seg * 8 + 3) * 72 + d];
            o1.x = t[(seg * 8 + 4) * 72 + d]; o1.y = t[(seg * 8 + 5) * 72 + d];
            o1.z = t[(seg * 8 + 6) * 72 + d]; o1.w = t[(seg * 8 + 7) * 72 + d];
            ushort* dst = xet + (size_t)(z * DMOD + d0 + d) * SRCN + x0 + seg * 8;
            *(ushort4*)dst = o0; *(ushort4*)(dst + 4) = o1;
        }
    }
}

// ---------------------------------------------------------------------------
// GEMM1 (full-K, no split): py = yce @ pwt^T + Pb, bf16 out.
// Tile 64m x 64n, BK=128 (two 64-k sub-chunks per barrier), K=2560 (20 iters).
// 512 blocks (2/CU), chunked XCD swizzle so same-m blocks share an L2.
// ---------------------------------------------------------------------------
__global__ __launch_bounds__(256) void k_gemm_py(
    const ushort* __restrict__ yce, const ushort* __restrict__ pwt,
    const float* __restrict__ Pb, ushort* __restrict__ py)
{
    __shared__ ushort As[2 * 8 * 512];   // 2 sub-k x (64 rows x 64 k)
    __shared__ ushort Bs[2 * 8 * 512];
    const int f = blockIdx.x;            // 0..511
    const int wg = ((f & 7) << 6) | (f >> 3);   // chunked per-XCD
    const int m = wg >> 3, n = wg & 7;   // 64 m x 8 n
    const int tid = threadIdx.x;
    const int w = tid >> 6, lane = tid & 63;
    const int l15 = lane & 15, q = lane >> 4;
    const int wm = w >> 1, wn = w & 1;
    const int m0 = m * 64, n0 = n * 64;

    const int sr = lane >> 3;
    const int ssg = ((lane & 7) ^ sr) * 8;

    const ushort* Abase = yce + (size_t)(m0 + sr) * 2560 + ssg;
    const ushort* Bbase = pwt + (size_t)(n0 + sr) * 2560 + ssg;

    floatx4 acc[2][2];
    #pragma unroll
    for (int mi = 0; mi < 2; ++mi)
        #pragma unroll
        for (int ni = 0; ni < 2; ++ni)
            acc[mi][ni] = (floatx4){0.f, 0.f, 0.f, 0.f};

    for (int kk = 0; kk < 2560; kk += 128) {
        __syncthreads();
        #pragma unroll
        for (int sub = 0; sub < 2; ++sub) {
            #pragma unroll
            for (int i = 0; i < 2; ++i) {
                const int cc = w * 2 + i;
                gload_lds16(Abase + (size_t)(cc * 8) * 2560 + kk + sub * 64,
                            (void*)(As + sub * 4096 + cc * 512));
                gload_lds16(Bbase + (size_t)(cc * 8) * 2560 + kk + sub * 64,
                            (void*)(Bs + sub * 4096 + cc * 512));
            }
        }
        __syncthreads();
        #pragma unroll
        for (int sub = 0; sub < 2; ++sub) {
            #pragma unroll
            for (int s2 = 0; s2 < 2; ++s2) {
                const int sg = s2 * 4 + q;
                short8 af[2], bf[2];
                #pragma unroll
                for (int mi = 0; mi < 2; ++mi)
                    af[mi] = *(const short8*)(As + sub * 4096 + LSLOT(wm * 32 + mi * 16 + l15, sg));
                #pragma unroll
                for (int ni = 0; ni < 2; ++ni)
                    bf[ni] = *(const short8*)(Bs + sub * 4096 + LSLOT(wn * 32 + ni * 16 + l15, sg));
                #pragma unroll
                for (int mi = 0; mi < 2; ++mi)
                    #pragma unroll
                    for (int ni = 0; ni < 2; ++ni)
                        acc[mi][ni] = __builtin_amdgcn_mfma_f32_16x16x32_bf16(
                            af[mi], bf[ni], acc[mi][ni], 0, 0, 0);
            }
        }
    }

    #pragma unroll
    for (int ni = 0; ni < 2; ++ni) {
        const int col = n0 + wn * 32 + ni * 16 + l15;
        const float bias = Pb[col];
        #pragma unroll
        for (int mi = 0; mi < 2; ++mi) {
            const int row0 = m0 + wm * 32 + mi * 16 + q * 4;
            #pragma unroll
            for (int r = 0; r < 4; ++r)
                py[(size_t)(row0 + r) * DMOD + col] = f2b(acc[mi][ni][r] + bias);
        }
    }
}

// ---------------------------------------------------------------------------
// GEMM2: a[b][0:128][n0:n0+64] = py_b @ xe_b^T (K=512), mask fused, fp32 out.
// Tile 128m x 64n, 512 blocks, per-batch XCD swizzle (f&7 == b&7).
// ---------------------------------------------------------------------------
__global__ __launch_bounds__(256) void k_gemm_sc(
    const ushort* __restrict__ py, const int* __restrict__ x,
    const ushort* __restrict__ xe, float* __restrict__ a_out)
{
    __shared__ ushort As[16 * 512];   // 128 rows x 64 k
    __shared__ ushort Bs[8 * 512];    // 64 rows x 64 k
    const int f = blockIdx.x;         // 0..511
    const int g = f >> 3;
    const int b = ((g & 3) << 3) | (f & 7);
    const int n = g >> 2;             // 0..15
    const int tid = threadIdx.x;
    const int w = tid >> 6, lane = tid & 63;
    const int l15 = lane & 15, q = lane >> 4;
    const int wm = w >> 1, wn = w & 1;
    const int n0 = n * 64;

    const int sr = lane >> 3;
    const int ssg = ((lane & 7) ^ sr) * 8;

    const ushort* Abase = py + (size_t)(b * SEQL + sr) * DMOD + ssg;
    const ushort* Bbase = xe + (size_t)(b * SRCN + n0 + sr) * DMOD + ssg;

    floatx4 acc[4][2];
    #pragma unroll
    for (int mi = 0; mi < 4; ++mi)
        #pragma unroll
        for (int ni = 0; ni < 2; ++ni)
            acc[mi][ni] = (floatx4){0.f, 0.f, 0.f, 0.f};

    for (int kk = 0; kk < DMOD; kk += 64) {
        __syncthreads();
        #pragma unroll
        for (int i = 0; i < 4; ++i) {
            const int cc = w * 4 + i;
            gload_lds16(Abase + (size_t)(cc * 8) * DMOD + kk, (void*)(As + cc * 512));
        }
        #pragma unroll
        for (int i = 0; i < 2; ++i) {
            const int cc = w * 2 + i;
            gload_lds16(Bbase + (size_t)(cc * 8) * DMOD + kk, (void*)(Bs + cc * 512));
        }
        __syncthreads();
        #pragma unroll
        for (int s2 = 0; s2 < 2; ++s2) {
            const int sg = s2 * 4 + q;
            short8 af[4], bf[2];
            #pragma unroll
            for (int mi = 0; mi < 4; ++mi)
                af[mi] = *(const short8*)(As + LSLOT(wm * 64 + mi * 16 + l15, sg));
            #pragma unroll
            for (int ni = 0; ni < 2; ++ni)
                bf[ni] = *(const short8*)(Bs + LSLOT(wn * 32 + ni * 16 + l15, sg));
            #pragma unroll
            for (int mi = 0; mi < 4; ++mi)
                #pragma unroll
                for (int ni = 0; ni < 2; ++ni)
                    acc[mi][ni] = __builtin_amdgcn_mfma_f32_16x16x32_bf16(
                        af[mi], bf[ni], acc[mi][ni], 0, 0, 0);
        }
    }

    #pragma unroll
    for (int ni = 0; ni < 2; ++ni) {
        const int col = n0 + wn * 32 + ni * 16 + l15;
        const float msk = (x[b * SRCN + col] == 0) ? -1e9f : 0.0f;
        #pragma unroll
        for (int mi = 0; mi < 4; ++mi) {
            const int row0 = wm * 64 + mi * 16 + q * 4;
            #pragma unroll
            for (int r = 0; r < 4; ++r)
                a_out[((size_t)b * SEQL + row0 + r) * SRCN + col] = acc[mi][ni][r] + msk;
        }
    }
}

// ---------------------------------------------------------------------------
// Row softmax over 1024 (mask already applied); fp32 in place + bf16 copy
// ---------------------------------------------------------------------------
__global__ __launch_bounds__(256) void k_softmax(
    float* __restrict__ a, ushort* __restrict__ abf)
{
    const int row = blockIdx.x;          // b*128+s
    float* p = a + (size_t)row * SRCN;
    ushort* pb = abf + (size_t)row * SRCN;
    const int tid = threadIdx.x;
    const int wave = tid >> 6, lane = tid & 63;

    float4 v = *(const float4*)(p + tid * 4);

    float mx = fmaxf(fmaxf(v.x, v.y), fmaxf(v.z, v.w));
    #pragma unroll
    for (int off = 32; off > 0; off >>= 1)
        mx = fmaxf(mx, __shfl_down(mx, off, 64));
    __shared__ float redm[4];
    if (lane == 0) redm[wave] = mx;
    __syncthreads();
    mx = fmaxf(fmaxf(redm[0], redm[1]), fmaxf(redm[2], redm[3]));

    const float e0 = __expf(v.x - mx);
    const float e1 = __expf(v.y - mx);
    const float e2 = __expf(v.z - mx);
    const float e3 = __expf(v.w - mx);

    float sm = e0 + e1 + e2 + e3;
    #pragma unroll
    for (int off = 32; off > 0; off >>= 1)
        sm += __shfl_down(sm, off, 64);
    __shared__ float reds[4];
    if (lane == 0) reds[wave] = sm;
    __syncthreads();
    sm = reds[0] + reds[1] + reds[2] + reds[3];

    const float inv = 1.0f / sm;
    float4 o;
    o.x = e0 * inv; o.y = e1 * inv; o.z = e2 * inv; o.w = e3 * inv;
    *(float4*)(p + tid * 4) = o;
    ushort4 ob;
    ob.x = f2b(o.x); ob.y = f2b(o.y); ob.z = f2b(o.z); ob.w = f2b(o.w);
    *(ushort4*)(pb + tid * 4) = ob;
}

// ---------------------------------------------------------------------------
// GEMM3: out[b][m0:m0+64][n0:n0+64] = abf_b @ xet_b^T (K=1024), fp32 out.
// Tile 64x64, BK=128 (two 64-k sub-chunks per barrier), 512 blocks.
// ---------------------------------------------------------------------------
__global__ __launch_bounds__(256) void k_gemm_out(
    const ushort* __restrict__ abf, const ushort* __restrict__ xet,
    float* __restrict__ outp)
{
    __shared__ ushort As[2 * 8 * 512];   // 2 sub-k x (64 rows x 64 k)
    __shared__ ushort Bs[2 * 8 * 512];
    const int f = blockIdx.x;            // 0..511
    const int g = f >> 3;
    const int b = ((g & 3) << 3) | (f & 7);
    const int h = g >> 2;                // 0..15
    const int m = h & 1, n = h >> 1;     // 2 m x 8 n
    const int tid = threadIdx.x;
    const int w = tid >> 6, lane = tid & 63;
    const int l15 = lane & 15, q = lane >> 4;
    const int wm = w >> 1, wn = w & 1;
    const int m0 = m * 64, n0 = n * 64;

    const int sr = lane >> 3;
    const int ssg = ((lane & 7) ^ sr) * 8;

    const ushort* Abase = abf + (size_t)(b * SEQL + m0 + sr) * SRCN + ssg;
    const ushort* Bbase = xet + (size_t)(b * DMOD + n0 + sr) * SRCN + ssg;

    floatx4 acc[2][2];
    #pragma unroll
    for (int mi = 0; mi < 2; ++mi)
        #pragma unroll
        for (int ni = 0; ni < 2; ++ni)
            acc[mi][ni] = (floatx4){0.f, 0.f, 0.f, 0.f};

    for (int kk = 0; kk < SRCN; kk += 128) {
        __syncthreads();
        #pragma unroll
        for (int sub = 0; sub < 2; ++sub) {
            #pragma unroll
            for (int i = 0; i < 2; ++i) {
                const int cc = w * 2 + i;
                gload_lds16(Abase + (size_t)(cc * 8) * SRCN + kk + sub * 64,
                            (void*)(As + sub * 4096 + cc * 512));
                gload_lds16(Bbase + (size_t)(cc * 8) * SRCN + kk + sub * 64,
                            (void*)(Bs + sub * 4096 + cc * 512));
            }
        }
        __syncthreads();
        #pragma unroll
        for (int sub = 0; sub < 2; ++sub) {
            #pragma unroll
            for (int s2 = 0; s2 < 2; ++s2) {
                const int sg = s2 * 4 + q;
                short8 af[2], bf[2];
                #pragma unroll
                for (int mi = 0; mi < 2; ++mi)
                    af[mi] = *(const short8*)(As + sub * 4096 + LSLOT(wm * 32 + mi * 16 + l15, sg));
                #pragma unroll
                for (int ni = 0; ni < 2; ++ni)
                    bf[ni] = *(const short8*)(Bs + sub * 4096 + LSLOT(wn * 32 + ni * 16 + l15, sg));
                #pragma unroll
                for (int mi = 0; mi < 2; ++mi)
                    #pragma unroll
                    for (int ni = 0; ni < 2; ++ni)
                        acc[mi][ni] = __builtin_amdgcn_mfma_f32_16x16x32_bf16(
                            af[mi], bf[ni], acc[mi][ni], 0, 0, 0);
            }
        }
    }

    #pragma unroll
    for (int ni = 0; ni < 2; ++ni) {
        const int col = n0 + wn * 32 + ni * 16 + l15;
        #pragma unroll
        for (int mi = 0; mi < 2; ++mi) {
            const int row0 = m0 + wm * 32 + mi * 16 + q * 4;
            #pragma unroll
            for (int r = 0; r < 4; ++r)
                outp[((size_t)b * SEQL + row0 + r) * DMOD + col] = acc[mi][ni][r];
        }
    }
}

// ---------------------------------------------------------------------------
extern "C" void kernel_launch(void* const* d_in, const int* in_sizes, int n_in,
                              void* d_out, int out_size, void* d_ws, size_t ws_size,
                              hipStream_t stream)
{
    const int*   x    = (const int*)d_in[0];    // [32,1024]
    const int*   yc   = (const int*)d_in[1];    // [32,640]
    const float* Femb = (const float*)d_in[2];  // [32000,512]
    const float* Gemb = (const float*)d_in[3];  // [32000,512]
    const float* Pw   = (const float*)d_in[4];  // [2560,512]
    const float* Pb   = (const float*)d_in[5];  // [512]

    float* out_p = (float*)d_out;                         // [32,128,512]
    float* a_p   = out_p + (size_t)BATCH * SEQL * DMOD;   // [32,128,1024]

    // Workspace (256 MiB available per fill evidence; peak used 94.9 MB):
    //   yce  [0,        20971520)  live: gather .. gemm_py
    //   abf  [0,         8388608)  live: softmax .. gemm_out (aliases dead yce)
    //   pwt  [20971520, 23592960)  live: gather .. gemm_py
    //   xe   [23592960, 57147392)  live: gather .. gemm_sc
    //   xet  [57147392, 90701824)  live: gather .. gemm_out
    //   py   [90701824, 94896128)  live: gemm_py .. gemm_sc
    char* ws = (char*)d_ws;
    ushort* yce  = (ushort*)(ws);
    ushort* abf  = (ushort*)(ws);
    ushort* pwt  = (ushort*)(ws + 20971520);
    ushort* xe   = (ushort*)(ws + 23592960);
    ushort* xet  = (ushort*)(ws + 57147392);
    ushort* py   = (ushort*)(ws + 90701824);

    dim3 blk(256);
    // all gathers in one launch (yce + pwt + xe/xet are independent)
    k_gather<<<dim3(8512), blk, 0, stream>>>(yc, Gemb, yce, Pw, pwt, x, Femb, xe, xet);

    // GEMM1 full-K (no split, no reduce pass), bias fused, bf16 out
    k_gemm_py<<<dim3(512), blk, 0, stream>>>(yce, pwt, Pb, py);

    // GEMM2 128x64 tiles: 512 blocks, mask fused
    k_gemm_sc<<<dim3(512), blk, 0, stream>>>(py, x, xe, a_p);
    k_softmax<<<dim3(4096), blk, 0, stream>>>(a_p, abf);
    // GEMM3 64x64 BK=128: 512 blocks
    k_gemm_out<<<dim3(512), blk, 0, stream>>>(abf, xet, out_p);
}